// Round 2
// baseline (2494.745 us; speedup 1.0000x reference)
//
#include <hip/hip_runtime.h>
#include <stdint.h>

#define B_ 8
#define D_ 128
#define T_ 4096
#define Q_ 30
#define C_ 1024

typedef __attribute__((ext_vector_type(8))) _Float16 half8;
typedef __attribute__((ext_vector_type(4))) float float4_;

// row-major fp16 codebook image [Q*C][128] — B-fragments load straight from here.
__device__ __align__(16) _Float16 g_half[(size_t)Q_*C_*D_];

// ---------------- prep 1: per-code ||c||^2, fp64 accumulation ----------------
__global__ void rvq_prep(const float* __restrict__ cb, float* __restrict__ sumsq){
  int g    = blockIdx.x*128 + (threadIdx.x>>1);
  int half = threadIdx.x & 1;
  const float* src = cb + (size_t)g*D_ + half*64;
  double s = 0.0;
#pragma unroll
  for (int i=0;i<64;i+=4){
    float4_ f = *(const float4_*)(src+i);
    s += (double)f.x*f.x + (double)f.y*f.y + (double)f.z*f.z + (double)f.w*f.w;
  }
  s += __shfl_xor(s, 1);
  if (!half) sumsq[g] = (float)s;
}

// ---------------- prep 2: fp32 -> fp16 codebook, row-major -------------------
__global__ void rvq_h(const float* __restrict__ cb){
  const size_t i = ((size_t)blockIdx.x*256 + threadIdx.x)*8;
  float4_ f0 = *(const float4_*)(cb + i);
  float4_ f1 = *(const float4_*)(cb + i + 4);
  half8 h;
  h[0]=(_Float16)f0.x; h[1]=(_Float16)f0.y; h[2]=(_Float16)f0.z; h[3]=(_Float16)f0.w;
  h[4]=(_Float16)f1.x; h[5]=(_Float16)f1.y; h[6]=(_Float16)f1.z; h[7]=(_Float16)f1.w;
  *(half8*)(g_half + i) = h;
}

// --- main: 30-step RVQ. 16 rows/wave, 512 blocks -> 2 blocks/CU.
// NOTE: no waves-per-EU bound — __launch_bounds__(256,2) forced VGPR=128
// (unified-pool split 128 VGPR + 128 AGPR) and spilled ~2 GB to scratch
// (round 1: WRITE_SIZE 1.25 GB, 2370 us). Natural alloc ~200 VGPR <= 256
// gives 2 waves/SIMD by hardware occupancy alone.
__global__ __launch_bounds__(256) void rvq_main(
    const float* __restrict__ x, const float* __restrict__ cb,
    const float* __restrict__ sumsq, double* __restrict__ lossAcc,
    float* __restrict__ out)
{
  __shared__ float sCS[4][16][34];   // per-wave packed top2 scores (stride 34)
  __shared__ int   sI4[4][16][4];    // per-row top-4 global code ids

  const int tid  = threadIdx.x;
  const int wv   = tid>>6;
  const int ln   = tid&63;
  const int col  = ln&15;
  const int quad = ln>>4;
  const int blk  = blockIdx.x;
  const int b    = blk>>6;
  const int t0   = ((blk&63)<<6) + (wv<<4);
  const int t    = t0 + col;

  // residual fp64, A-frag distribution: row = col, dim = kc*32+quad*8+j
  double rmast[4][8];
#pragma unroll
  for (int kc=0;kc<4;++kc)
#pragma unroll
    for (int j=0;j<8;++j){
      const int d = kc*32 + quad*8 + j;
      rmast[kc][j] = (double)x[((size_t)b*D_ + d)*T_ + t];
    }

  half8 ah[4];
  auto makeAB = [&](){
#pragma unroll
    for (int kc=0;kc<4;++kc){
      half8 h;
#pragma unroll
      for (int j=0;j<8;++j) h[j] = (_Float16)(float)rmast[kc][j];
      ah[kc] = h;
    }
  };
  makeAB();

  double lossd = 0.0;

  // register pipeline buffers: B-fragments + cc for one group (32 codes)
  half8 bufA[8], bufB[8];
  float ccA[2],  ccB[2];

  auto loadGroup = [&](const _Float16* cbh, const float* ssq, int g, half8* Bv, float* cc){
#pragma unroll
    for (int kc=0;kc<4;++kc)
#pragma unroll
      for (int ct=0;ct<2;++ct){
        const int n = g*32 + ct*16 + col;
        Bv[kc*2+ct] = *(const half8*)(cbh + n*128 + kc*32 + quad*8);
      }
#pragma unroll
    for (int ct=0;ct<2;++ct)
      cc[ct] = ssq[(g*2+ct)*16 + col];
  };

  loadGroup(g_half, sumsq, 0, bufA, ccA);   // prologue: q=0, group 0

  for (int q=0;q<Q_;++q){
    const float*    cbq = cb     + (size_t)q*C_*D_;
    const _Float16* cbh = g_half + (size_t)q*C_*D_;
    const float*    ssq = sumsq  + q*C_;

    // packed top-2 per cell: score float with low 6 mantissa bits = cid (0..63)
    float p1[4], p2[4];
#pragma unroll
    for (int rg=0;rg<4;++rg){ p1[rg]=3.0e38f; p2[rg]=3.0e38f; }

#pragma unroll
    for (int g=0; g<32; ++g){
      half8* cur = (g&1) ? bufB : bufA;
      float* ccc = (g&1) ? ccB  : ccA;
      // prefetch next group (codebook loads independent of residual —
      // cross-q prefetch of (q+1, group 0) overlaps the q-tail)
      if (g < 31){
        loadGroup(cbh, ssq, g+1, (g&1)?bufA:bufB, (g&1)?ccA:ccB);
      } else if (q+1 < Q_){
        loadGroup(cbh + C_*D_, ssq + C_, 0, (g&1)?bufA:bufB, (g&1)?ccA:ccB);
      }

      float4_ acc[2];
#pragma unroll
      for (int ct=0;ct<2;++ct) acc[ct] = (float4_){0.f,0.f,0.f,0.f};
#pragma unroll
      for (int kc=0;kc<4;++kc)
#pragma unroll
        for (int ct=0;ct<2;++ct)
          acc[ct] = __builtin_amdgcn_mfma_f32_16x16x32_f16(ah[kc], cur[kc*2+ct], acc[ct], 0,0,0);

#pragma unroll
      for (int ct=0;ct<2;++ct){
        const int cid = g*2 + ct;                      // global code = cid*16+col
#pragma unroll
        for (int rg=0;rg<4;++rg){
          float sc = fmaf(-2.0f, acc[ct][rg], ccc[ct]);
          unsigned u = (__builtin_bit_cast(unsigned, sc) & ~63u) | (unsigned)cid;
          float sp = __builtin_bit_cast(float, u);
          if (sp < p1[rg]) { p2[rg]=p1[rg]; p1[rg]=sp; }
          else if (sp < p2[rg]) { p2[rg]=sp; }
        }
      }
    }

    // ---- publish per-lane packed top-2 (wave-private, lockstep) ----
#pragma unroll
    for (int rg=0;rg<4;++rg){
      const int row = quad*4 + rg;
      sCS[wv][row][col*2+0] = p1[rg];
      sCS[wv][row][col*2+1] = p2[rg];
    }

    // ---- lanes 0..15: scan own row's 32 packed entries -> top-4 ids ----
    if (ln < 16){
      const int row = ln;
      float b0=3.0e38f,b1=3.0e38f,b2=3.0e38f,b3=3.0e38f;
      int   e0=0,e1=0,e2=0,e3=0;
#pragma unroll
      for (int c2=0;c2<32;++c2){
        const float sc = sCS[wv][row][c2];
        const int   id = (((__builtin_bit_cast(unsigned, sc)) & 63u)<<4) + (c2>>1);
        const bool l0 = (sc<b0);
        const bool l1 = (sc<b1);
        const bool l2 = (sc<b2);
        const bool l3 = (sc<b3);
        if (l3){
          b3 = l2 ? b2 : sc;  e3 = l2 ? e2 : id;
          if (l2){
            b2 = l1 ? b1 : sc;  e2 = l1 ? e1 : id;
            if (l1){
              b1 = l0 ? b0 : sc;  e1 = l0 ? e0 : id;
              if (l0){ b0 = sc; e0 = id; }
            }
          }
        }
      }
      sI4[wv][row][0]=e0; sI4[wv][row][1]=e1; sI4[wv][row][2]=e2; sI4[wv][row][3]=e3;
    }

    // ---- fp64 exact rescore of top-4, winner update (wave-private) ----------
    {
      const int m = col;
      double bestS = 1.0e300; int bestJ = 0x7fffffff;
#pragma unroll
      for (int cnd=0;cnd<4;++cnd){
        const int jj = sI4[wv][m][cnd];
        const float* p = cbq + ((size_t)jj<<7) + (quad<<3);
        double sd = 0.0;
#pragma unroll
        for (int kc=0;kc<4;++kc){
          float4_ a0 = *(const float4_*)(p + kc*32);
          float4_ a1 = *(const float4_*)(p + kc*32 + 4);
          float fv[8] = {a0.x,a0.y,a0.z,a0.w,a1.x,a1.y,a1.z,a1.w};
#pragma unroll
          for (int j=0;j<8;++j){
            double cd = (double)fv[j];
            sd += cd*(cd - 2.0*rmast[kc][j]);
          }
        }
        sd += __shfl_xor(sd, 16); sd += __shfl_xor(sd, 32);
        if ((sd < bestS) || (sd == bestS && jj < bestJ)){ bestS = sd; bestJ = jj; }
      }
      const float* pw = cbq + ((size_t)bestJ<<7) + (quad<<3);
#pragma unroll
      for (int kc=0;kc<4;++kc){
        float4_ w0 = *(const float4_*)(pw + kc*32);
        float4_ w1 = *(const float4_*)(pw + kc*32 + 4);
        float fw[8] = {w0.x,w0.y,w0.z,w0.w,w1.x,w1.y,w1.z,w1.w};
#pragma unroll
        for (int j=0;j<8;++j){
          double rn = rmast[kc][j] - (double)fw[j];
          rmast[kc][j] = rn;
          lossd += rn*rn;
        }
      }
    }
    makeAB();
  }

  // ---- epilogue: quantized = x - r_final ----
#pragma unroll
  for (int kc=0;kc<4;++kc)
#pragma unroll
    for (int j=0;j<8;++j){
      const int d = kc*32 + quad*8 + j;
      const size_t o = ((size_t)b*D_ + d)*T_ + t;
      out[o] = (float)((double)x[o] - rmast[kc][j]);
    }
#pragma unroll
  for (int mk=1; mk<64; mk<<=1) lossd += __shfl_xor(lossd, mk);
  if (ln==0) atomicAdd(lossAcc, lossd);
}

__global__ void rvq_fin(const double* __restrict__ lossAcc, float* __restrict__ out){
  out[(size_t)B_*D_*T_] = (float)(*lossAcc * (1.0/((double)B_*(double)D_*(double)T_)));
}

extern "C" void kernel_launch(void* const* d_in, const int* in_sizes, int n_in,
                              void* d_out, int out_size, void* d_ws, size_t ws_size,
                              hipStream_t stream) {
  const float* x  = (const float*)d_in[0];   // [B, D, T] fp32
  const float* cb = (const float*)d_in[1];   // [Q, C, D] fp32
  float* out      = (float*)d_out;           // [B*D*T] quantized + [1] loss
  double* lossAcc = (double*)d_ws;
  float*  sumsq   = (float*)((char*)d_ws + 256);   // Q*C floats

  hipMemsetAsync(d_ws, 0, 256, stream);
  rvq_prep<<<Q_*C_/128, 256, 0, stream>>>(cb, sumsq);
  rvq_h   <<<(Q_*C_*D_)/(256*8), 256, 0, stream>>>(cb);
  rvq_main<<<(B_*T_)/64, 256, 0, stream>>>(x, cb, sumsq, lossAcc, out);
  rvq_fin <<<1, 1, 0, stream>>>(lossAcc, out);
}

// Round 4
// 2095.795 us; speedup vs baseline: 1.1904x; 1.1904x over previous
//
#include <hip/hip_runtime.h>
#include <stdint.h>

#define B_ 8
#define D_ 128
#define T_ 4096
#define Q_ 30
#define C_ 1024

typedef __attribute__((ext_vector_type(8))) _Float16 half8;
typedef __attribute__((ext_vector_type(4))) float float4_;

// row-major fp16 codebook image [Q*C][128] — B-fragments load straight from here.
__device__ __align__(16) _Float16 g_half[(size_t)Q_*C_*D_];

// ---------------- prep 1: per-code ||c||^2, fp64 accumulation ----------------
__global__ void rvq_prep(const float* __restrict__ cb, float* __restrict__ sumsq){
  int g    = blockIdx.x*128 + (threadIdx.x>>1);
  int half = threadIdx.x & 1;
  const float* src = cb + (size_t)g*D_ + half*64;
  double s = 0.0;
#pragma unroll
  for (int i=0;i<64;i+=4){
    float4_ f = *(const float4_*)(src+i);
    s += (double)f.x*f.x + (double)f.y*f.y + (double)f.z*f.z + (double)f.w*f.w;
  }
  s += __shfl_xor(s, 1);
  if (!half) sumsq[g] = (float)s;
}

// ---------------- prep 2: fp32 -> fp16 codebook, row-major -------------------
__global__ void rvq_h(const float* __restrict__ cb){
  const size_t i = ((size_t)blockIdx.x*256 + threadIdx.x)*8;
  float4_ f0 = *(const float4_*)(cb + i);
  float4_ f1 = *(const float4_*)(cb + i + 4);
  half8 h;
  h[0]=(_Float16)f0.x; h[1]=(_Float16)f0.y; h[2]=(_Float16)f0.z; h[3]=(_Float16)f0.w;
  h[4]=(_Float16)f1.x; h[5]=(_Float16)f1.y; h[6]=(_Float16)f1.z; h[7]=(_Float16)f1.w;
  *(half8*)(g_half + i) = h;
}

// --- main: 30-step RVQ. 16 rows/wave, 512 blocks, target 2 waves/SIMD.
// Lessons wired in:
//  - rmast MUST be fp64: the np reference is an fp64 chain; fp32 residual
//    diverges on near-tie code selections and cascades (round 3: absmax 6.86).
//  - 2 waves/SIMD requires TOTAL (arch+acc) regs <= 256; the unconstrained
//    allocator burns >256 (round 2: 224 arch + parked AGPRs -> 12% occupancy).
//    So: __launch_bounds__(256,2) caps the budget, and the structure is slimmed
//    to fit it with margin (~155 live): single-buffered B-frags, rolled g-loop.
//    (Round 1 spilled under this cap because dbuf+full-unroll needed ~290.)
//  - no runtime-selected buffer pointers in the rolled loop (rule #20).
__global__ __launch_bounds__(256,2) void rvq_main(
    const float* __restrict__ x, const float* __restrict__ cb,
    const float* __restrict__ sumsq, double* __restrict__ lossAcc,
    float* __restrict__ out)
{
  __shared__ float sCS[4][16][34];   // per-wave packed top2 scores (stride 34)
  __shared__ int   sI4[4][16][4];    // per-row top-4 global code ids

  const int tid  = threadIdx.x;
  const int wv   = tid>>6;
  const int ln   = tid&63;
  const int col  = ln&15;
  const int quad = ln>>4;
  const int blk  = blockIdx.x;
  const int b    = blk>>6;
  const int t0   = ((blk&63)<<6) + (wv<<4);
  const int t    = t0 + col;

  // residual fp64, A-frag distribution: row = col, dim = kc*32+quad*8+j
  double rmast[4][8];
#pragma unroll
  for (int kc=0;kc<4;++kc)
#pragma unroll
    for (int j=0;j<8;++j){
      const int d = kc*32 + quad*8 + j;
      rmast[kc][j] = (double)x[((size_t)b*D_ + d)*T_ + t];
    }

  half8 ah[4];
  auto makeAB = [&](){
#pragma unroll
    for (int kc=0;kc<4;++kc){
      half8 h;
#pragma unroll
      for (int j=0;j<8;++j) h[j] = (_Float16)(float)rmast[kc][j];
      ah[kc] = h;
    }
  };
  makeAB();

  double lossd = 0.0;

  // single-buffered B-fragments + cc for one group (32 codes)
  half8 buf[8];
  float cc[2];

  for (int q=0;q<Q_;++q){
    const float*    cbq = cb     + (size_t)q*C_*D_;
    const _Float16* cbh = g_half + (size_t)q*C_*D_;
    const float*    ssq = sumsq  + q*C_;

    // packed top-2 per cell: score float with low 6 mantissa bits = cid (0..63)
    float p1[4], p2[4];
#pragma unroll
    for (int rg=0;rg<4;++rg){ p1[rg]=3.0e38f; p2[rg]=3.0e38f; }

#pragma unroll 1
    for (int g=0; g<32; ++g){
      // load this group's B-fragments (8x 16B from L2-resident fp16 image)
#pragma unroll
      for (int kc=0;kc<4;++kc)
#pragma unroll
        for (int ct=0;ct<2;++ct){
          const int n = g*32 + ct*16 + col;
          buf[kc*2+ct] = *(const half8*)(cbh + n*128 + kc*32 + quad*8);
        }
#pragma unroll
      for (int ct=0;ct<2;++ct)
        cc[ct] = ssq[(g*2+ct)*16 + col];

      float4_ acc[2];
#pragma unroll
      for (int ct=0;ct<2;++ct) acc[ct] = (float4_){0.f,0.f,0.f,0.f};
#pragma unroll
      for (int kc=0;kc<4;++kc)
#pragma unroll
        for (int ct=0;ct<2;++ct)
          acc[ct] = __builtin_amdgcn_mfma_f32_16x16x32_f16(ah[kc], buf[kc*2+ct], acc[ct], 0,0,0);

#pragma unroll
      for (int ct=0;ct<2;++ct){
        const int cid = g*2 + ct;                      // global code = cid*16+col
#pragma unroll
        for (int rg=0;rg<4;++rg){
          float sc = fmaf(-2.0f, acc[ct][rg], cc[ct]);
          unsigned u = (__builtin_bit_cast(unsigned, sc) & ~63u) | (unsigned)cid;
          float sp = __builtin_bit_cast(float, u);
          if (sp < p1[rg]) { p2[rg]=p1[rg]; p1[rg]=sp; }
          else if (sp < p2[rg]) { p2[rg]=sp; }
        }
      }
    }

    // ---- publish per-lane packed top-2 (wave-private, lockstep) ----
#pragma unroll
    for (int rg=0;rg<4;++rg){
      const int row = quad*4 + rg;
      sCS[wv][row][col*2+0] = p1[rg];
      sCS[wv][row][col*2+1] = p2[rg];
    }

    // ---- lanes 0..15: scan own row's 32 packed entries -> top-4 ids ----
    if (ln < 16){
      const int row = ln;
      float b0=3.0e38f,b1=3.0e38f,b2=3.0e38f,b3=3.0e38f;
      int   e0=0,e1=0,e2=0,e3=0;
#pragma unroll
      for (int c2=0;c2<32;++c2){
        const float sc = sCS[wv][row][c2];
        const int   id = (((__builtin_bit_cast(unsigned, sc)) & 63u)<<4) + (c2>>1);
        const bool l0 = (sc<b0);
        const bool l1 = (sc<b1);
        const bool l2 = (sc<b2);
        const bool l3 = (sc<b3);
        if (l3){
          b3 = l2 ? b2 : sc;  e3 = l2 ? e2 : id;
          if (l2){
            b2 = l1 ? b1 : sc;  e2 = l1 ? e1 : id;
            if (l1){
              b1 = l0 ? b0 : sc;  e1 = l0 ? e0 : id;
              if (l0){ b0 = sc; e0 = id; }
            }
          }
        }
      }
      sI4[wv][row][0]=e0; sI4[wv][row][1]=e1; sI4[wv][row][2]=e2; sI4[wv][row][3]=e3;
    }

    // ---- fp64 exact rescore of top-4, winner update (wave-private) ----------
    {
      const int m = col;
      double bestS = 1.0e300; int bestJ = 0x7fffffff;
#pragma unroll
      for (int cnd=0;cnd<4;++cnd){
        const int jj = sI4[wv][m][cnd];
        const float* p = cbq + ((size_t)jj<<7) + (quad<<3);
        double sd = 0.0;
#pragma unroll
        for (int kc=0;kc<4;++kc){
          float4_ a0 = *(const float4_*)(p + kc*32);
          float4_ a1 = *(const float4_*)(p + kc*32 + 4);
          float fv[8] = {a0.x,a0.y,a0.z,a0.w,a1.x,a1.y,a1.z,a1.w};
#pragma unroll
          for (int j=0;j<8;++j){
            double cd = (double)fv[j];
            sd += cd*(cd - 2.0*rmast[kc][j]);
          }
        }
        sd += __shfl_xor(sd, 16); sd += __shfl_xor(sd, 32);
        if ((sd < bestS) || (sd == bestS && jj < bestJ)){ bestS = sd; bestJ = jj; }
      }
      const float* pw = cbq + ((size_t)bestJ<<7) + (quad<<3);
#pragma unroll
      for (int kc=0;kc<4;++kc){
        float4_ w0 = *(const float4_*)(pw + kc*32);
        float4_ w1 = *(const float4_*)(pw + kc*32 + 4);
        float fw[8] = {w0.x,w0.y,w0.z,w0.w,w1.x,w1.y,w1.z,w1.w};
#pragma unroll
        for (int j=0;j<8;++j){
          double rn = rmast[kc][j] - (double)fw[j];
          rmast[kc][j] = rn;
          lossd += rn*rn;
        }
      }
    }
    makeAB();
  }

  // ---- epilogue: quantized = x - r_final ----
#pragma unroll
  for (int kc=0;kc<4;++kc)
#pragma unroll
    for (int j=0;j<8;++j){
      const int d = kc*32 + quad*8 + j;
      const size_t o = ((size_t)b*D_ + d)*T_ + t;
      out[o] = (float)((double)x[o] - rmast[kc][j]);
    }
#pragma unroll
  for (int mk=1; mk<64; mk<<=1) lossd += __shfl_xor(lossd, mk);
  if (ln==0) atomicAdd(lossAcc, lossd);
}

__global__ void rvq_fin(const double* __restrict__ lossAcc, float* __restrict__ out){
  out[(size_t)B_*D_*T_] = (float)(*lossAcc * (1.0/((double)B_*(double)D_*(double)T_)));
}

extern "C" void kernel_launch(void* const* d_in, const int* in_sizes, int n_in,
                              void* d_out, int out_size, void* d_ws, size_t ws_size,
                              hipStream_t stream) {
  const float* x  = (const float*)d_in[0];   // [B, D, T] fp32
  const float* cb = (const float*)d_in[1];   // [Q, C, D] fp32
  float* out      = (float*)d_out;           // [B*D*T] quantized + [1] loss
  double* lossAcc = (double*)d_ws;
  float*  sumsq   = (float*)((char*)d_ws + 256);   // Q*C floats

  hipMemsetAsync(d_ws, 0, 256, stream);
  rvq_prep<<<Q_*C_/128, 256, 0, stream>>>(cb, sumsq);
  rvq_h   <<<(Q_*C_*D_)/(256*8), 256, 0, stream>>>(cb);
  rvq_main<<<(B_*T_)/64, 256, 0, stream>>>(x, cb, sumsq, lossAcc, out);
  rvq_fin <<<1, 1, 0, stream>>>(lossAcc, out);
}